// Round 1
// baseline (394.294 us; speedup 1.0000x reference)
//
#include <hip/hip_runtime.h>

#define NCH      256
#define NNB      262144
#define BN       64
#define NTILES   (NNB / BN)
#define NTHREADS 512

typedef __bf16        bf16x8 __attribute__((ext_vector_type(8)));
typedef float         f32x4  __attribute__((ext_vector_type(4)));
typedef unsigned int  u32x4  __attribute__((ext_vector_type(4)));

union FragU { u32x4 u; bf16x8 b; };

__device__ __forceinline__ unsigned int bf16_rne(float f) {
    unsigned int u = __float_as_uint(f);
    return (u + 0x7fffu + ((u >> 16) & 1u)) >> 16;
}
__device__ __forceinline__ unsigned int pack2(float lo, float hi) {
    return bf16_rne(lo) | (bf16_rne(hi) << 16);
}

// Kernel 1: per-block partial A over a grid-strided set of 64-column tiles.
// ws layout: [block][k=256][6 symmetric (d,e) entries] fp32
__global__ __launch_bounds__(NTHREADS, 2) void create_As_k1(
        const float* __restrict__ h, const float* __restrict__ rp,
        const float* __restrict__ W, float* __restrict__ ws, int nblocks)
{
    __shared__ unsigned short htile[BN * NCH];   // 32 KB bf16, [i-row][j], XOR-swizzled
    __shared__ float radial[NCH * 66];           // 67.5 KB, [k][col], stride 66 (bank pad)
    __shared__ float uu6[6][BN];                 // 1.5 KB

    const int t    = threadIdx.x;
    const int wave = t >> 6;        // 0..7 -> k range [wave*32, wave*32+32)
    const int il   = t & 15;        // lane % 16
    const int q    = (t >> 4) & 3;  // (lane / 16) & 3

    // ---- W fragments (MFMA A operand), register-resident for whole kernel ----
    // A-frag (16x16x32): lane holds W[k0 + (l&15)][jb*32 + q*8 + e], e=0..7
    FragU wf[2][8];
    #pragma unroll
    for (int kt = 0; kt < 2; ++kt) {
        const int k = wave * 32 + kt * 16 + il;
        const float* wr = W + (size_t)k * NCH + q * 8;
        #pragma unroll
        for (int jb = 0; jb < 8; ++jb) {
            f32x4 a = *(const f32x4*)(wr + jb * 32);
            f32x4 b = *(const f32x4*)(wr + jb * 32 + 4);
            FragU f;
            f.u[0] = pack2(a[0], a[1]);
            f.u[1] = pack2(a[2], a[3]);
            f.u[2] = pack2(b[0], b[1]);
            f.u[3] = pack2(b[2], b[3]);
            wf[kt][jb] = f;
        }
    }

    // per-lane A accumulators: 8 k-slots (kt*4+r) x 6 symmetric (d,e)
    float acc6[8][6];
    #pragma unroll
    for (int s = 0; s < 8; ++s)
        #pragma unroll
        for (int m = 0; m < 6; ++m) acc6[s][m] = 0.0f;

    for (int tile = blockIdx.x; tile < NTILES; tile += nblocks) {
        const size_t i0 = (size_t)tile * BN;
        __syncthreads();   // previous compute phase done before LDS overwrite

        // ---- per-column geometry (each thread computes its own column's d) ----
        const int c = t & 63;
        float px = rp[i0 + c];
        float py = rp[(size_t)NNB + i0 + c];
        float pz = rp[2 * (size_t)NNB + i0 + c];
        float d2   = px * px + py * py + pz * pz;
        float dd   = sqrtf(d2);
        float invd = 1.0f / dd;
        if (t < 64) {
            float inv2 = invd * invd;
            uu6[0][c] = px * px * inv2;
            uu6[1][c] = px * py * inv2;
            uu6[2][c] = px * pz * inv2;
            uu6[3][c] = py * py * inv2;
            uu6[4][c] = py * pz * inv2;
            uu6[5][c] = pz * pz * inv2;
        }

        // ---- radial table: sin((k+1)*d)/d via rotation recurrence ----
        // thread (c = t&63, chunk = wave) fills k in [chunk*32, chunk*32+32)
        {
            const int chunk = wave;
            float s, co, s1, c1;
            sincosf((float)(chunk * 32 + 1) * dd, &s, &co);
            sincosf(dd, &s1, &c1);
            float* rr = &radial[(size_t)(chunk * 32) * 66 + c];
            #pragma unroll 8
            for (int m = 0; m < 32; ++m) {
                rr[(size_t)m * 66] = s * invd;
                float ns = s * c1 + co * s1;
                co = co * c1 - s * s1;
                s  = ns;
            }
        }

        // ---- stage h tile: fp32 -> bf16, LDS [i][j] with XOR swizzle ----
        // lane = column (coalesced dword loads across lanes), 8 j's per pack
        {
            const int ir = t & 63;
            #pragma unroll
            for (int pp = 0; pp < 4; ++pp) {
                const int jp = pp * 8 + wave;    // 0..31 (8-j packs)
                const float* src = h + (size_t)(jp * 8) * NNB + i0 + ir;
                float v0 = src[0];
                float v1 = src[(size_t)NNB];
                float v2 = src[2 * (size_t)NNB];
                float v3 = src[3 * (size_t)NNB];
                float v4 = src[4 * (size_t)NNB];
                float v5 = src[5 * (size_t)NNB];
                float v6 = src[6 * (size_t)NNB];
                float v7 = src[7 * (size_t)NNB];
                u32x4 pk;
                pk[0] = pack2(v0, v1);
                pk[1] = pack2(v2, v3);
                pk[2] = pack2(v4, v5);
                pk[3] = pack2(v6, v7);
                unsigned off = ((unsigned)(ir * 512 + jp * 16)) ^ ((unsigned)(ir & 7) << 4);
                *(u32x4*)((char*)htile + off) = pk;
            }
        }
        __syncthreads();

        // ---- MFMA hp = W @ h_tile, fused radial/uu epilogue ----
        #pragma unroll
        for (int cb = 0; cb < 4; ++cb) {
            const int ic = cb * 16 + il;
            f32x4 acc0 = {0.f, 0.f, 0.f, 0.f};
            f32x4 acc1 = {0.f, 0.f, 0.f, 0.f};
            const unsigned rbase = (unsigned)(ic * 512);
            const unsigned sw    = (unsigned)(il & 7) << 4;
            #pragma unroll
            for (int jb = 0; jb < 8; ++jb) {
                unsigned off = (rbase + (unsigned)((jb * 32 + q * 8) * 2)) ^ sw;
                FragU bfr;
                bfr.u = *(const u32x4*)((const char*)htile + off);
                acc0 = __builtin_amdgcn_mfma_f32_16x16x32_bf16(wf[0][jb].b, bfr.b, acc0, 0, 0, 0);
                acc1 = __builtin_amdgcn_mfma_f32_16x16x32_bf16(wf[1][jb].b, bfr.b, acc1, 0, 0, 0);
            }
            const float u0 = uu6[0][ic], u1 = uu6[1][ic], u2 = uu6[2][ic];
            const float u3 = uu6[3][ic], u4 = uu6[4][ic], u5 = uu6[5][ic];
            const int kb = wave * 32 + q * 4;
            #pragma unroll
            for (int r = 0; r < 4; ++r) {
                float m0 = radial[(size_t)(kb + r) * 66 + ic] * acc0[r];
                acc6[r][0] += m0 * u0; acc6[r][1] += m0 * u1; acc6[r][2] += m0 * u2;
                acc6[r][3] += m0 * u3; acc6[r][4] += m0 * u4; acc6[r][5] += m0 * u5;
                float m1 = radial[(size_t)(kb + 16 + r) * 66 + ic] * acc1[r];
                acc6[4 + r][0] += m1 * u0; acc6[4 + r][1] += m1 * u1; acc6[4 + r][2] += m1 * u2;
                acc6[4 + r][3] += m1 * u3; acc6[4 + r][4] += m1 * u4; acc6[4 + r][5] += m1 * u5;
            }
        }
    }

    // ---- reduce over the 16 column-lanes sharing each k-set ----
    #pragma unroll
    for (int s = 0; s < 8; ++s)
        #pragma unroll
        for (int m = 0; m < 6; ++m) {
            float v = acc6[s][m];
            v += __shfl_xor(v, 1);
            v += __shfl_xor(v, 2);
            v += __shfl_xor(v, 4);
            v += __shfl_xor(v, 8);
            acc6[s][m] = v;
        }
    if (il == 0) {
        float* dst = ws + (size_t)blockIdx.x * (NCH * 6);
        #pragma unroll
        for (int kt = 0; kt < 2; ++kt)
            #pragma unroll
            for (int r = 0; r < 4; ++r) {
                const int k = wave * 32 + kt * 16 + q * 4 + r;
                #pragma unroll
                for (int m = 0; m < 6; ++m)
                    dst[k * 6 + m] = acc6[kt * 4 + r][m];
            }
    }
}

// Kernel 2: reduce block partials, expand symmetric 6 -> 3x3
__global__ void create_As_k2(const float* __restrict__ ws, float* __restrict__ out,
                             int nblocks)
{
    int tid = blockIdx.x * blockDim.x + threadIdx.x;
    if (tid >= NCH * 9) return;
    int k  = tid / 9;
    int de = tid % 9;
    int d = de / 3, e = de % 3;
    int lo = d < e ? d : e;
    int hi = d < e ? e : d;
    int m6 = (lo == 0) ? hi : (lo == 1 ? 2 + hi : 5);
    float sum = 0.f;
    for (int b = 0; b < nblocks; ++b)
        sum += ws[(size_t)b * (NCH * 6) + k * 6 + m6];
    out[tid] = sum;
}

extern "C" void kernel_launch(void* const* d_in, const int* in_sizes, int n_in,
                              void* d_out, int out_size, void* d_ws, size_t ws_size,
                              hipStream_t stream)
{
    const float* h  = (const float*)d_in[0];
    const float* rp = (const float*)d_in[1];
    const float* W  = (const float*)d_in[2];
    float* out = (float*)d_out;
    float* ws  = (float*)d_ws;

    const size_t per_block = (size_t)NCH * 6 * sizeof(float);
    int nb = (int)(ws_size / per_block);
    if (nb > 1024) nb = 1024;
    if (nb < 1)    nb = 1;

    hipLaunchKernelGGL(create_As_k1, dim3(nb), dim3(NTHREADS), 0, stream,
                       h, rp, W, ws, nb);
    hipLaunchKernelGGL(create_As_k2, dim3(9), dim3(256), 0, stream, ws, out, nb);
}

// Round 2
// 156.307 us; speedup vs baseline: 2.5226x; 2.5226x over previous
//
#include <hip/hip_runtime.h>

#define NCH      256
#define NNB      262144
#define BN       64
#define NTILES   (NNB / BN)
#define NTHREADS 512

typedef __bf16        bf16x8 __attribute__((ext_vector_type(8)));
typedef float         f32x4  __attribute__((ext_vector_type(4)));
typedef unsigned int  u32x4  __attribute__((ext_vector_type(4)));
typedef unsigned int  u32x2  __attribute__((ext_vector_type(2)));

union FragU { u32x4 u; bf16x8 b; };

__device__ __forceinline__ unsigned int bf16_rne(float f) {
    unsigned int u = __float_as_uint(f);
    return (u + 0x7fffu + ((u >> 16) & 1u)) >> 16;
}
__device__ __forceinline__ unsigned int pack2(float lo, float hi) {
    return bf16_rne(lo) | (bf16_rne(hi) << 16);
}
__device__ __forceinline__ float bf16lo_f(unsigned int w) { return __uint_as_float(w << 16); }
__device__ __forceinline__ float bf16hi_f(unsigned int w) { return __uint_as_float(w & 0xffff0000u); }

// raw barrier: lets prefetch global loads stay in flight (no vmcnt drain).
// lgkmcnt(0) ensures our LDS writes are visible before other waves read.
#define LBAR() do {                                                  \
    asm volatile("s_waitcnt lgkmcnt(0)" ::: "memory");               \
    __builtin_amdgcn_sched_barrier(0);                               \
    __builtin_amdgcn_s_barrier();                                    \
    __builtin_amdgcn_sched_barrier(0);                               \
} while (0)

// Kernel 1: per-block partial A over grid-strided 64-column tiles.
// ws layout (TRANSPOSED): [entry = k*6+m6][block]  -> contiguous reduce rows for K2.
__global__ __launch_bounds__(NTHREADS, 2) void create_As_k1(
        const float* __restrict__ h, const float* __restrict__ rp,
        const float* __restrict__ W, float* __restrict__ ws, int nb)
{
    __shared__ unsigned short htile[BN * NCH];   // 32 KB bf16 [col][j], XOR-swizzled
    __shared__ unsigned short radlds[BN * NCH];  // 32 KB bf16 [col][k], XOR-swizzled
    __shared__ float uu6[6][BN];                 // 1.5 KB

    const int t    = threadIdx.x;
    const int wave = t >> 6;        // 0..7 -> k range [wave*32, wave*32+32)
    const int il   = t & 15;
    const int q    = (t >> 4) & 3;
    const int c    = t & 63;        // column within tile

    // ---- W fragments (MFMA A operand), register-resident ----
    FragU wf[2][8];
    #pragma unroll
    for (int kt = 0; kt < 2; ++kt) {
        const int k = wave * 32 + kt * 16 + il;
        const float* wr = W + (size_t)k * NCH + q * 8;
        #pragma unroll
        for (int jb = 0; jb < 8; ++jb) {
            f32x4 a = *(const f32x4*)(wr + jb * 32);
            f32x4 b = *(const f32x4*)(wr + jb * 32 + 4);
            FragU f;
            f.u[0] = pack2(a[0], a[1]);
            f.u[1] = pack2(a[2], a[3]);
            f.u[2] = pack2(b[0], b[1]);
            f.u[3] = pack2(b[2], b[3]);
            wf[kt][jb] = f;
        }
    }

    float acc6[8][6];
    #pragma unroll
    for (int s = 0; s < 8; ++s)
        #pragma unroll
        for (int m = 0; m < 6; ++m) acc6[s][m] = 0.0f;

    // ---- prefetch state (registers) ----
    float hv[32];
    float px, py, pz;

    // prologue: issue loads for first tile
    {
        const size_t i0 = (size_t)blockIdx.x * BN;
        const float* rpc = rp + i0 + c;
        px = rpc[0]; py = rpc[(size_t)NNB]; pz = rpc[2 * (size_t)NNB];
        #pragma unroll
        for (int pp = 0; pp < 4; ++pp) {
            const int jp = pp * 8 + wave;
            const float* src = h + (size_t)(jp * 8) * NNB + i0 + c;
            #pragma unroll
            for (int j = 0; j < 8; ++j) hv[pp * 8 + j] = src[(size_t)j * NNB];
        }
    }

    for (int tile = blockIdx.x; tile < NTILES; tile += nb) {
        // ================= phase A: regs -> LDS =================
        float dd   = sqrtf(px * px + py * py + pz * pz);
        float invd = 1.0f / dd;
        if (t < 64) {
            float inv2 = invd * invd;
            uu6[0][c] = px * px * inv2;
            uu6[1][c] = px * py * inv2;
            uu6[2][c] = px * pz * inv2;
            uu6[3][c] = py * py * inv2;
            uu6[4][c] = py * pz * inv2;
            uu6[5][c] = pz * pz * inv2;
        }

        // radial chunk: k in [wave*32, wave*32+32) for column c, bf16, b128 writes
        {
            float s0, c0, s1, c1;
            __sincosf((float)(wave * 32 + 1) * dd, &s0, &c0);
            __sincosf(dd, &s1, &c1);
            unsigned rw[16];
            float s = s0, co = c0;
            #pragma unroll
            for (int m = 0; m < 16; ++m) {
                float v0 = s * invd;
                float ns = s * c1 + co * s1; co = co * c1 - s * s1; s = ns;
                float v1 = s * invd;
                ns = s * c1 + co * s1; co = co * c1 - s * s1; s = ns;
                rw[m] = pack2(v0, v1);
            }
            #pragma unroll
            for (int g = 0; g < 4; ++g) {
                u32x4 pk = { rw[g * 4], rw[g * 4 + 1], rw[g * 4 + 2], rw[g * 4 + 3] };
                unsigned off = ((unsigned)(c * 512 + wave * 64 + g * 16)) ^ ((unsigned)(c & 7) << 4);
                *(u32x4*)((char*)radlds + off) = pk;
            }
        }

        // h tile: fp32 regs -> bf16 LDS [col][j], b128 writes
        #pragma unroll
        for (int pp = 0; pp < 4; ++pp) {
            const int jp = pp * 8 + wave;
            u32x4 pk;
            pk[0] = pack2(hv[pp * 8 + 0], hv[pp * 8 + 1]);
            pk[1] = pack2(hv[pp * 8 + 2], hv[pp * 8 + 3]);
            pk[2] = pack2(hv[pp * 8 + 4], hv[pp * 8 + 5]);
            pk[3] = pack2(hv[pp * 8 + 6], hv[pp * 8 + 7]);
            unsigned off = ((unsigned)(c * 512 + jp * 16)) ^ ((unsigned)(c & 7) << 4);
            *(u32x4*)((char*)htile + off) = pk;
        }

        LBAR();

        // ================= phase B: prefetch next + compute =================
        {
            const int nxt = tile + nb;
            const int lt  = (nxt < NTILES) ? nxt : tile;   // clamp: harmless reload
            const size_t i0n = (size_t)lt * BN;
            const float* rpc = rp + i0n + c;
            px = rpc[0]; py = rpc[(size_t)NNB]; pz = rpc[2 * (size_t)NNB];
            #pragma unroll
            for (int pp = 0; pp < 4; ++pp) {
                const int jp = pp * 8 + wave;
                const float* src = h + (size_t)(jp * 8) * NNB + i0n + c;
                #pragma unroll
                for (int j = 0; j < 8; ++j) hv[pp * 8 + j] = src[(size_t)j * NNB];
            }
        }
        __builtin_amdgcn_sched_barrier(0);   // pin prefetch issue before compute

        #pragma unroll
        for (int cb = 0; cb < 4; ++cb) {
            const int ic = cb * 16 + il;
            f32x4 acc0 = {0.f, 0.f, 0.f, 0.f};
            f32x4 acc1 = {0.f, 0.f, 0.f, 0.f};
            const unsigned rbase = (unsigned)(ic * 512);
            const unsigned sw    = ((unsigned)(ic & 7)) << 4;
            #pragma unroll
            for (int jb = 0; jb < 8; ++jb) {
                unsigned off = (rbase + (unsigned)(jb * 64 + q * 16)) ^ sw;
                FragU bfr;
                bfr.u = *(const u32x4*)((const char*)htile + off);
                acc0 = __builtin_amdgcn_mfma_f32_16x16x32_bf16(wf[0][jb].b, bfr.b, acc0, 0, 0, 0);
                acc1 = __builtin_amdgcn_mfma_f32_16x16x32_bf16(wf[1][jb].b, bfr.b, acc1, 0, 0, 0);
            }
            const int kb = wave * 32 + q * 4;
            u32x2 r0 = *(const u32x2*)((const char*)radlds + ((rbase + (unsigned)(kb * 2)) ^ sw));
            u32x2 r1 = *(const u32x2*)((const char*)radlds + ((rbase + (unsigned)((kb + 16) * 2)) ^ sw));
            float rad0[4] = { bf16lo_f(r0[0]), bf16hi_f(r0[0]), bf16lo_f(r0[1]), bf16hi_f(r0[1]) };
            float rad1[4] = { bf16lo_f(r1[0]), bf16hi_f(r1[0]), bf16lo_f(r1[1]), bf16hi_f(r1[1]) };
            const float u0 = uu6[0][ic], u1 = uu6[1][ic], u2 = uu6[2][ic];
            const float u3 = uu6[3][ic], u4 = uu6[4][ic], u5 = uu6[5][ic];
            #pragma unroll
            for (int r = 0; r < 4; ++r) {
                float m0 = rad0[r] * acc0[r];
                acc6[r][0] += m0 * u0; acc6[r][1] += m0 * u1; acc6[r][2] += m0 * u2;
                acc6[r][3] += m0 * u3; acc6[r][4] += m0 * u4; acc6[r][5] += m0 * u5;
                float m1 = rad1[r] * acc1[r];
                acc6[4 + r][0] += m1 * u0; acc6[4 + r][1] += m1 * u1; acc6[4 + r][2] += m1 * u2;
                acc6[4 + r][3] += m1 * u3; acc6[4 + r][4] += m1 * u4; acc6[4 + r][5] += m1 * u5;
            }
        }

        __builtin_amdgcn_sched_barrier(0);
        __builtin_amdgcn_s_barrier();        // reads of htile/radlds done; A may overwrite
        __builtin_amdgcn_sched_barrier(0);
    }

    // ---- reduce over the 16 column-lanes, write transposed partials ----
    #pragma unroll
    for (int s = 0; s < 8; ++s)
        #pragma unroll
        for (int m = 0; m < 6; ++m) {
            float v = acc6[s][m];
            v += __shfl_xor(v, 1);
            v += __shfl_xor(v, 2);
            v += __shfl_xor(v, 4);
            v += __shfl_xor(v, 8);
            acc6[s][m] = v;
        }
    if (il == 0) {
        #pragma unroll
        for (int kt = 0; kt < 2; ++kt)
            #pragma unroll
            for (int r = 0; r < 4; ++r) {
                const int k = wave * 32 + kt * 16 + q * 4 + r;
                #pragma unroll
                for (int m = 0; m < 6; ++m)
                    ws[(size_t)(k * 6 + m) * nb + blockIdx.x] = acc6[kt * 4 + r][m];
            }
    }
}

// Kernel 2: one wave per output element; coalesced contiguous reduce rows.
__global__ void create_As_k2(const float* __restrict__ ws, float* __restrict__ out,
                             int nb)
{
    const int wv   = (int)((blockIdx.x * blockDim.x + threadIdx.x) >> 6);
    const int lane = threadIdx.x & 63;
    if (wv >= NCH * 9) return;
    const int k  = wv / 9;
    const int de = wv % 9;
    const int d = de / 3, e = de % 3;
    const int lo = d < e ? d : e;
    const int hi = d < e ? e : d;
    const int m6 = (lo == 0) ? hi : (lo == 1 ? 2 + hi : 5);
    const float* src = ws + (size_t)(k * 6 + m6) * nb;
    float s = 0.f;
    for (int b = lane; b < nb; b += 64) s += src[b];
    s += __shfl_xor(s, 1);
    s += __shfl_xor(s, 2);
    s += __shfl_xor(s, 4);
    s += __shfl_xor(s, 8);
    s += __shfl_xor(s, 16);
    s += __shfl_xor(s, 32);
    if (lane == 0) out[wv] = s;
}

extern "C" void kernel_launch(void* const* d_in, const int* in_sizes, int n_in,
                              void* d_out, int out_size, void* d_ws, size_t ws_size,
                              hipStream_t stream)
{
    const float* h  = (const float*)d_in[0];
    const float* rp = (const float*)d_in[1];
    const float* W  = (const float*)d_in[2];
    float* out = (float*)d_out;
    float* ws  = (float*)d_ws;

    const size_t per_block = (size_t)NCH * 6 * sizeof(float);
    int nb = (int)(ws_size / per_block);
    if (nb > 512)    nb = 512;
    if (nb > NTILES) nb = NTILES;
    if (nb < 1)      nb = 1;

    hipLaunchKernelGGL(create_As_k1, dim3(nb), dim3(NTHREADS), 0, stream,
                       h, rp, W, ws, nb);
    // 2304 output elements, one wave each -> 576 blocks of 256 threads
    hipLaunchKernelGGL(create_As_k2, dim3((NCH * 9 * 64) / 256), dim3(256), 0, stream,
                       ws, out, nb);
}